// Round 5
// baseline (912.876 us; speedup 1.0000x reference)
//
#include <hip/hip_runtime.h>
#include <hip/hip_bf16.h>

#define EPS_BN 1e-5f

using short8  = __attribute__((ext_vector_type(8))) short;
using ushort8 = __attribute__((ext_vector_type(8))) unsigned short;
using f32x4   = __attribute__((ext_vector_type(4))) float;

__device__ inline float bf2f(unsigned short u) {
    union { unsigned i; float f; } c; c.i = ((unsigned)u) << 16; return c.f;
}
__device__ inline unsigned short f2bf(float f) {
    unsigned x = __float_as_uint(f);
    unsigned r = (x + 0x7FFF + ((x >> 16) & 1)) >> 16;   // RNE
    return (unsigned short)r;
}

// ---------------------------------------------------------------- utilities
__global__ void zero_i32(int* __restrict__ p, int n) {
    int i = blockIdx.x * blockDim.x + threadIdx.x;
    if (i < n) p[i] = 0;
}
__global__ void zero_f32(float* __restrict__ p, int n) {
    int i = blockIdx.x * blockDim.x + threadIdx.x;
    if (i < n) p[i] = 0.0f;
}

// fp32 [R][C] -> bf16 [R][CP], zero-padded columns
__global__ void conv_w(const float* __restrict__ w, unsigned short* __restrict__ o,
                       int R, int C, int CP) {
    int t = blockIdx.x * blockDim.x + threadIdx.x;
    if (t >= R * CP) return;
    int r = t / CP, c = t % CP;
    o[t] = (c < C) ? f2bf(w[(size_t)r * C + c]) : (unsigned short)0;
}

// x [n][100] f32 -> xpad [n][128] bf16 (zero pad)
__global__ void conv_x_pad(const float* __restrict__ x, unsigned short* __restrict__ xp, int n) {
    int t = blockIdx.x * blockDim.x + threadIdx.x;
    if (t >= n * 32) return;
    int node = t >> 5, g = t & 31;
    int f0 = g * 4;
    ushort4 o;
    const float* xr = x + (size_t)node * 100;
    o.x = (f0 + 0 < 100) ? f2bf(xr[f0 + 0]) : 0;
    o.y = (f0 + 1 < 100) ? f2bf(xr[f0 + 1]) : 0;
    o.z = (f0 + 2 < 100) ? f2bf(xr[f0 + 2]) : 0;
    o.w = (f0 + 3 < 100) ? f2bf(xr[f0 + 3]) : 0;
    *(ushort4*)(xp + (size_t)node * 128 + f0) = o;
}

// ---------------------------------------------------------------- CSR build
__global__ void count_k(const int* __restrict__ dst, int* __restrict__ counts, int E) {
    int i = blockIdx.x * blockDim.x + threadIdx.x;
    if (i < E) atomicAdd(&counts[dst[i]], 1);
}

__global__ void scan1(const int* __restrict__ counts, int* __restrict__ rp,
                      int* __restrict__ partials, int n) {
    __shared__ int s[256];
    int t = threadIdx.x;
    int i = blockIdx.x * 256 + t;
    int v = (i < n) ? counts[i] : 0;
    s[t] = v;
    __syncthreads();
    for (int off = 1; off < 256; off <<= 1) {
        int u = (t >= off) ? s[t - off] : 0;
        __syncthreads();
        s[t] += u;
        __syncthreads();
    }
    if (i < n) rp[i] = s[t] - v;
    if (t == 255) partials[blockIdx.x] = s[255];
}

__global__ void scan2(int* __restrict__ partials, int nb) {
    __shared__ int s[512];
    int t = threadIdx.x;
    int v = (t < nb) ? partials[t] : 0;
    s[t] = v;
    __syncthreads();
    for (int off = 1; off < 512; off <<= 1) {
        int u = (t >= off) ? s[t - off] : 0;
        __syncthreads();
        s[t] += u;
        __syncthreads();
    }
    if (t < nb) partials[t] = s[t] - v;
}

__global__ void scan3(int* __restrict__ rp, const int* __restrict__ partials, int n, int E) {
    int i = blockIdx.x * blockDim.x + threadIdx.x;
    if (i < n) rp[i] += partials[i >> 8];
    if (i == 0) rp[n] = E;
}

__global__ void fill_k(const int* __restrict__ src, const int* __restrict__ dst,
                       const int* __restrict__ rp, int* __restrict__ cursor,
                       int* __restrict__ col, int E) {
    int i = blockIdx.x * blockDim.x + threadIdx.x;
    if (i < E) {
        int d = dst[i];
        int pos = atomicAdd(&cursor[d], 1);
        col[rp[d] + pos] = src[i];
    }
}

// ------------------------------------------------------- gather aggregation
__global__ __launch_bounds__(256) void agg_bf16_256(
    const unsigned short* __restrict__ x, const int* __restrict__ rp,
    const int* __restrict__ col, unsigned short* __restrict__ out, int n) {
    int wave = threadIdx.x >> 6, lane = threadIdx.x & 63;
    int node = blockIdx.x * 4 + wave;
    if (node >= n) return;
    int s = rp[node], e = rp[node + 1];
    int deg = e - s;
    int h = lane >> 5;
    int l32 = lane & 31;

    float a[8] = {0, 0, 0, 0, 0, 0, 0, 0};
    int base = 0;
    for (; base + 8 <= deg; base += 8) {
        int i = s + base + h;
        int r0 = col[i], r1 = col[i + 2], r2 = col[i + 4], r3 = col[i + 6];
        ushort8 v0 = *(const ushort8*)(x + (size_t)r0 * 256 + l32 * 8);
        ushort8 v1 = *(const ushort8*)(x + (size_t)r1 * 256 + l32 * 8);
        ushort8 v2 = *(const ushort8*)(x + (size_t)r2 * 256 + l32 * 8);
        ushort8 v3 = *(const ushort8*)(x + (size_t)r3 * 256 + l32 * 8);
#pragma unroll
        for (int j = 0; j < 8; ++j)
            a[j] += bf2f(v0[j]) + bf2f(v1[j]) + bf2f(v2[j]) + bf2f(v3[j]);
    }
    for (int i = s + base + h; i < e; i += 2) {
        int r = col[i];
        ushort8 v = *(const ushort8*)(x + (size_t)r * 256 + l32 * 8);
#pragma unroll
        for (int j = 0; j < 8; ++j) a[j] += bf2f(v[j]);
    }
#pragma unroll
    for (int j = 0; j < 8; ++j) a[j] += __shfl_xor(a[j], 32);

    if (h == 0) {
        float sc = 1.0f / fmaxf((float)deg, 1.0f);
        ushort8 o;
#pragma unroll
        for (int j = 0; j < 8; ++j) o[j] = f2bf(a[j] * sc);
        *(ushort8*)(out + (size_t)node * 256 + l32 * 8) = o;
    }
}

__global__ __launch_bounds__(256) void agg_bf16_128(
    const unsigned short* __restrict__ x, const int* __restrict__ rp,
    const int* __restrict__ col, unsigned short* __restrict__ out, int n) {
    int wave = threadIdx.x >> 6, lane = threadIdx.x & 63;
    int node = blockIdx.x * 4 + wave;
    if (node >= n) return;
    int s = rp[node], e = rp[node + 1];
    int deg = e - s;
    int q = lane >> 4;
    int l16 = lane & 15;

    float a[8] = {0, 0, 0, 0, 0, 0, 0, 0};
    int base = 0;
    for (; base + 16 <= deg; base += 16) {
        int i = s + base + q;
        int r0 = col[i], r1 = col[i + 4], r2 = col[i + 8], r3 = col[i + 12];
        ushort8 v0 = *(const ushort8*)(x + (size_t)r0 * 128 + l16 * 8);
        ushort8 v1 = *(const ushort8*)(x + (size_t)r1 * 128 + l16 * 8);
        ushort8 v2 = *(const ushort8*)(x + (size_t)r2 * 128 + l16 * 8);
        ushort8 v3 = *(const ushort8*)(x + (size_t)r3 * 128 + l16 * 8);
#pragma unroll
        for (int j = 0; j < 8; ++j)
            a[j] += bf2f(v0[j]) + bf2f(v1[j]) + bf2f(v2[j]) + bf2f(v3[j]);
    }
    for (int i = s + base + q; i < e; i += 4) {
        int r = col[i];
        ushort8 v = *(const ushort8*)(x + (size_t)r * 128 + l16 * 8);
#pragma unroll
        for (int j = 0; j < 8; ++j) a[j] += bf2f(v[j]);
    }
#pragma unroll
    for (int j = 0; j < 8; ++j) {
        a[j] += __shfl_xor(a[j], 16);
        a[j] += __shfl_xor(a[j], 32);
    }

    if (lane < 16) {
        float sc = 1.0f / fmaxf((float)deg, 1.0f);
        ushort8 o;
#pragma unroll
        for (int j = 0; j < 8; ++j) o[j] = f2bf(a[j] * sc);
        *(ushort8*)(out + (size_t)node * 128 + l16 * 8) = o;
    }
}

// ------------------------------------------------- fused SAGE linear (MFMA)
// Register-tiled, no LDS: 512 threads = 8 waves (WAVES_M x WAVES_N).
// Each wave: 64 nodes x 64 cols = 4x4 16x16 tiles; A-frags from global
// (streamed, L2/L3), B-frags (weights) from global (L2-resident).
// 2-stage software pipeline (even/odd register sets), fully unrolled K.
template <int KTOT, int DOUT, bool HAS_AGG, bool RELU, bool STF32, bool STBF16, int WAVES_M>
__global__ __launch_bounds__(512) void sage_mfma(
    const unsigned short* __restrict__ xp, const unsigned short* __restrict__ ap,
    const unsigned short* __restrict__ Wr, const unsigned short* __restrict__ Wl,
    const float* __restrict__ bias,
    float* __restrict__ outf, unsigned short* __restrict__ outb, int n) {
    constexpr int WAVES_N = 8 / WAVES_M;   // 4 (DOUT=256) or 2 (DOUT=128)
    constexpr int KS = KTOT / 32;
    static_assert(DOUT / 16 / WAVES_N == 4, "wave owns 4 col tiles");

    const int t = threadIdx.x;
    const int wave = t >> 6, lane = t & 63;
    const int wm = wave / WAVES_N, wn = wave % WAVES_N;
    const int lcol = lane & 15, lq = lane >> 4;
    const int node_base = blockIdx.x * (WAVES_M * 64) + wm * 64;
    const int col0 = wn * 64;

    f32x4 acc[4][4];
#pragma unroll
    for (int ct = 0; ct < 4; ++ct) {
        float b = bias[col0 + ct * 16 + lcol];
#pragma unroll
        for (int mt = 0; mt < 4; ++mt) {
            acc[mt][ct][0] = b; acc[mt][ct][1] = b; acc[mt][ct][2] = b; acc[mt][ct][3] = b;
        }
    }

    const unsigned short* aPx[4];
    const unsigned short* aPa[4];
    const unsigned short* bPr[4];
    const unsigned short* bPl[4];
#pragma unroll
    for (int i = 0; i < 4; ++i) {
        aPx[i] = xp + (size_t)(node_base + i * 16 + lcol) * KTOT + lq * 8;
        bPr[i] = Wr + (size_t)(col0 + i * 16 + lcol) * KTOT + lq * 8;
        if (HAS_AGG) {
            aPa[i] = ap + (size_t)(node_base + i * 16 + lcol) * KTOT + lq * 8;
            bPl[i] = Wl + (size_t)(col0 + i * 16 + lcol) * KTOT + lq * 8;
        }
    }

    short8 axE[4], aaE[4], brE[4], blE[4];
    short8 axO[4], aaO[4], brO[4], blO[4];

    auto LOAD = [&](int ks, short8 (&ax)[4], short8 (&aa)[4],
                    short8 (&br)[4], short8 (&bl)[4]) {
#pragma unroll
        for (int i = 0; i < 4; ++i) {
            ax[i] = *(const short8*)(aPx[i] + ks * 32);
            br[i] = *(const short8*)(bPr[i] + ks * 32);
        }
        if constexpr (HAS_AGG) {
#pragma unroll
            for (int i = 0; i < 4; ++i) {
                aa[i] = *(const short8*)(aPa[i] + ks * 32);
                bl[i] = *(const short8*)(bPl[i] + ks * 32);
            }
        }
    };
    auto MM = [&](short8 (&ax)[4], short8 (&aa)[4],
                  short8 (&br)[4], short8 (&bl)[4]) {
#pragma unroll
        for (int mt = 0; mt < 4; ++mt)
#pragma unroll
            for (int ct = 0; ct < 4; ++ct) {
                acc[mt][ct] = __builtin_amdgcn_mfma_f32_16x16x32_bf16(
                    ax[mt], br[ct], acc[mt][ct], 0, 0, 0);
                if constexpr (HAS_AGG)
                    acc[mt][ct] = __builtin_amdgcn_mfma_f32_16x16x32_bf16(
                        aa[mt], bl[ct], acc[mt][ct], 0, 0, 0);
            }
    };

    LOAD(0, axE, aaE, brE, blE);
#pragma unroll
    for (int ks = 0; ks < KS; ks += 2) {
        LOAD(ks + 1, axO, aaO, brO, blO);
        MM(axE, aaE, brE, blE);
        if (ks + 2 < KS) LOAD(ks + 2, axE, aaE, brE, blE);
        MM(axO, aaO, brO, blO);
    }

#pragma unroll
    for (int mt = 0; mt < 4; ++mt) {
        int nb0 = node_base + mt * 16;
        if (nb0 >= n) continue;          // n % 16 == 0 -> tile all-valid or empty
#pragma unroll
        for (int ct = 0; ct < 4; ++ct) {
            f32x4 v = acc[mt][ct];
            if (RELU) {
                v[0] = fmaxf(v[0], 0.0f); v[1] = fmaxf(v[1], 0.0f);
                v[2] = fmaxf(v[2], 0.0f); v[3] = fmaxf(v[3], 0.0f);
            }
            int colI = col0 + ct * 16 + lcol;
#pragma unroll
            for (int j = 0; j < 4; ++j) {
                size_t row = (size_t)nb0 + lq * 4 + j;
                if (STF32) outf[row * DOUT + colI] = v[j];
                if (STBF16) outb[row * DOUT + colI] = f2bf(v[j]);
            }
        }
    }
}

// ---------------------------------------------------------------- BatchNorm
__global__ void bn_partial(const float* __restrict__ z, float* __restrict__ sums, int n) {
    int f = threadIdx.x & 127;
    int half = threadIdx.x >> 7;
    float s = 0.0f, s2 = 0.0f;
    for (int row = blockIdx.x * 2 + half; row < n; row += gridDim.x * 2) {
        float v = z[(size_t)row * 128 + f];
        s += v; s2 += v * v;
    }
    __shared__ float ls[256], ls2[256];
    ls[threadIdx.x] = s; ls2[threadIdx.x] = s2;
    __syncthreads();
    if (half == 0) {
        atomicAdd(&sums[f], s + ls[128 + f]);
        atomicAdd(&sums[128 + f], s2 + ls2[128 + f]);
    }
}

__global__ void bn_finalize(const float* __restrict__ sums, const float* __restrict__ gamma,
                            const float* __restrict__ beta, float* __restrict__ params, int n) {
    int f = threadIdx.x;  // 128 threads
    float mu = sums[f] / (float)n;
    float var = sums[128 + f] / (float)n - mu * mu;
    float inv = rsqrtf(var + EPS_BN);
    float sc = gamma[f] * inv;
    params[f] = sc;
    params[128 + f] = beta[f] - mu * sc;
}

__global__ void bn_apply(float* __restrict__ z, const float* __restrict__ params, int total4) {
    int i = blockIdx.x * blockDim.x + threadIdx.x;
    for (; i < total4; i += gridDim.x * blockDim.x) {
        float4 v = ((float4*)z)[i];
        int f0 = (i & 31) * 4;
        v.x = v.x * params[f0 + 0] + params[128 + f0 + 0];
        v.y = v.y * params[f0 + 1] + params[128 + f0 + 1];
        v.z = v.z * params[f0 + 2] + params[128 + f0 + 2];
        v.w = v.w * params[f0 + 3] + params[128 + f0 + 3];
        ((float4*)z)[i] = v;
    }
}

// ---------------------------------------------------------------- launcher
extern "C" void kernel_launch(void* const* d_in, const int* in_sizes, int n_in,
                              void* d_out, int out_size, void* d_ws, size_t ws_size,
                              hipStream_t stream) {
    const float* x_in  = (const float*)d_in[0];
    const int*   ei    = (const int*)d_in[1];
    const float* Wl0   = (const float*)d_in[2];
    const float* bl0   = (const float*)d_in[3];
    const float* Wr0   = (const float*)d_in[4];
    const float* Wl1   = (const float*)d_in[5];
    const float* bl1   = (const float*)d_in[6];
    const float* Wr1   = (const float*)d_in[7];
    const float* Wl2   = (const float*)d_in[8];
    const float* bl2   = (const float*)d_in[9];
    const float* Wr2   = (const float*)d_in[10];
    const float* Wp    = (const float*)d_in[11];
    const float* bp    = (const float*)d_in[12];
    const float* gamma = (const float*)d_in[13];
    const float* beta  = (const float*)d_in[14];

    const int IN = 100, INP = 128, H = 256, OUT = 256, P = 128;
    const int n = in_sizes[0] / IN;          // 100000
    const int E = in_sizes[1] / 2;           // 1600000
    const int* src = ei;
    const int* dst = ei + E;

    size_t off = 0;
    auto alloc = [&](size_t bytes) -> char* {
        char* p = (char*)d_ws + off;
        off += (bytes + 255) & ~(size_t)255;
        return p;
    };
    int*   counts   = (int*)alloc((size_t)n * 4);
    int*   cursor   = (int*)alloc((size_t)n * 4);
    int*   rp       = (int*)alloc((size_t)(n + 1) * 4);
    int*   partials = (int*)alloc(512 * 4);
    int*   col      = (int*)alloc((size_t)E * 4);
    unsigned short* Wl0b = (unsigned short*)alloc((size_t)H * INP * 2);
    unsigned short* Wr0b = (unsigned short*)alloc((size_t)H * INP * 2);
    unsigned short* Wl1b = (unsigned short*)alloc((size_t)H * H * 2);
    unsigned short* Wr1b = (unsigned short*)alloc((size_t)H * H * 2);
    unsigned short* Wl2b = (unsigned short*)alloc((size_t)OUT * H * 2);
    unsigned short* Wr2b = (unsigned short*)alloc((size_t)OUT * H * 2);
    unsigned short* Wpb  = (unsigned short*)alloc((size_t)P * OUT * 2);
    float* bnsums   = (float*)alloc(256 * 4);
    float* bnparams = (float*)alloc(256 * 4);
    unsigned short* bufA = (unsigned short*)alloc((size_t)n * H * 2);
    unsigned short* bufB = (unsigned short*)alloc((size_t)n * H * 2);
    unsigned short* bufC = (unsigned short*)alloc((size_t)n * H * 2);
    unsigned short* bufD = (unsigned short*)alloc((size_t)n * H * 2);
    (void)alloc((size_t)256 * 512);                      // OOB guard for last tile reads

    unsigned short* xpad   = bufA;                        // [n][128]
    unsigned short* aggpad = bufA + (size_t)n * INP;      // [n][128]
    unsigned short* h1b  = bufB;
    unsigned short* agg1 = bufC;
    unsigned short* h2b  = bufD;
    unsigned short* agg2 = bufB;                          // reuse (h1 dead)
    unsigned short* xb2  = bufA;                          // reuse (xpad/aggpad dead)

    float* out_x = (float*)d_out;                  // [n][256] final x
    float* z     = out_x + (size_t)n * OUT;        // [n][128] projection/BN output

    const int nb = (n + 255) / 256;

    // --- CSR build ---
    zero_i32<<<nb, 256, 0, stream>>>(counts, n);
    zero_i32<<<nb, 256, 0, stream>>>(cursor, n);
    zero_f32<<<1, 256, 0, stream>>>(bnsums, 256);
    count_k<<<(E + 255) / 256, 256, 0, stream>>>(dst, counts, E);
    scan1<<<nb, 256, 0, stream>>>(counts, rp, partials, n);
    scan2<<<1, 512, 0, stream>>>(partials, nb);
    scan3<<<nb, 256, 0, stream>>>(rp, partials, n, E);
    fill_k<<<(E + 255) / 256, 256, 0, stream>>>(src, dst, rp, cursor, col, E);

    // --- dtype conversions ---
    conv_x_pad<<<(n * 32 + 255) / 256, 256, 0, stream>>>(x_in, xpad, n);
    conv_w<<<(H * INP + 255) / 256, 256, 0, stream>>>(Wl0, Wl0b, H, IN, INP);
    conv_w<<<(H * INP + 255) / 256, 256, 0, stream>>>(Wr0, Wr0b, H, IN, INP);
    conv_w<<<(H * H + 255) / 256, 256, 0, stream>>>(Wl1, Wl1b, H, H, H);
    conv_w<<<(H * H + 255) / 256, 256, 0, stream>>>(Wr1, Wr1b, H, H, H);
    conv_w<<<(OUT * H + 255) / 256, 256, 0, stream>>>(Wl2, Wl2b, OUT, H, H);
    conv_w<<<(OUT * H + 255) / 256, 256, 0, stream>>>(Wr2, Wr2b, OUT, H, H);
    conv_w<<<(P * OUT + 255) / 256, 256, 0, stream>>>(Wp, Wpb, P, OUT, OUT);

    // --- layer 0: 128(pad) -> 256, relu ---
    agg_bf16_128<<<(n + 3) / 4, 256, 0, stream>>>(xpad, rp, col, aggpad, n);
    sage_mfma<128, 256, true, true, false, true, 2><<<(n + 127) / 128, 512, 0, stream>>>(
        xpad, aggpad, Wr0b, Wl0b, bl0, nullptr, h1b, n);

    // --- layer 1: 256 -> 256, relu ---
    agg_bf16_256<<<(n + 3) / 4, 256, 0, stream>>>(h1b, rp, col, agg1, n);
    sage_mfma<256, 256, true, true, false, true, 2><<<(n + 127) / 128, 512, 0, stream>>>(
        h1b, agg1, Wr1b, Wl1b, bl1, nullptr, h2b, n);

    // --- layer 2: 256 -> 256, no relu; f32 -> d_out, bf16 copy for projection ---
    agg_bf16_256<<<(n + 3) / 4, 256, 0, stream>>>(h2b, rp, col, agg2, n);
    sage_mfma<256, 256, true, false, true, true, 2><<<(n + 127) / 128, 512, 0, stream>>>(
        h2b, agg2, Wr2b, Wl2b, bl2, out_x, xb2, n);

    // --- projection head: 256 -> 128 ---
    sage_mfma<256, 128, false, false, true, false, 4><<<(n + 255) / 256, 512, 0, stream>>>(
        xb2, nullptr, Wpb, nullptr, bp, z, nullptr, n);

    // --- BatchNorm over z ---
    bn_partial<<<256, 256, 0, stream>>>(z, bnsums, n);
    bn_finalize<<<1, 128, 0, stream>>>(bnsums, gamma, beta, bnparams, n);
    bn_apply<<<2048, 256, 0, stream>>>(z, bnparams, n * (P / 4));
}

// Round 6
// 767.014 us; speedup vs baseline: 1.1902x; 1.1902x over previous
//
#include <hip/hip_runtime.h>
#include <hip/hip_bf16.h>

#define EPS_BN 1e-5f

using short8  = __attribute__((ext_vector_type(8))) short;
using ushort8 = __attribute__((ext_vector_type(8))) unsigned short;
using f32x4   = __attribute__((ext_vector_type(4))) float;

typedef const __attribute__((address_space(1))) void* gas_ptr;
typedef __attribute__((address_space(3))) void* las_ptr;

__device__ inline float bf2f(unsigned short u) {
    union { unsigned i; float f; } c; c.i = ((unsigned)u) << 16; return c.f;
}
__device__ inline unsigned short f2bf(float f) {
    unsigned x = __float_as_uint(f);
    unsigned r = (x + 0x7FFF + ((x >> 16) & 1)) >> 16;   // RNE
    return (unsigned short)r;
}

// ---------------------------------------------------------------- utilities
__global__ void zero_i32(int* __restrict__ p, int n) {
    int i = blockIdx.x * blockDim.x + threadIdx.x;
    if (i < n) p[i] = 0;
}
__global__ void zero_f32(float* __restrict__ p, int n) {
    int i = blockIdx.x * blockDim.x + threadIdx.x;
    if (i < n) p[i] = 0.0f;
}

// fp32 [R][C] -> bf16 [R][CP], zero-padded columns
__global__ void conv_w(const float* __restrict__ w, unsigned short* __restrict__ o,
                       int R, int C, int CP) {
    int t = blockIdx.x * blockDim.x + threadIdx.x;
    if (t >= R * CP) return;
    int r = t / CP, c = t % CP;
    o[t] = (c < C) ? f2bf(w[(size_t)r * C + c]) : (unsigned short)0;
}

// x [n][100] f32 -> xpad [n][128] bf16 (zero pad)
__global__ void conv_x_pad(const float* __restrict__ x, unsigned short* __restrict__ xp, int n) {
    int t = blockIdx.x * blockDim.x + threadIdx.x;
    if (t >= n * 32) return;
    int node = t >> 5, g = t & 31;
    int f0 = g * 4;
    ushort4 o;
    const float* xr = x + (size_t)node * 100;
    o.x = (f0 + 0 < 100) ? f2bf(xr[f0 + 0]) : 0;
    o.y = (f0 + 1 < 100) ? f2bf(xr[f0 + 1]) : 0;
    o.z = (f0 + 2 < 100) ? f2bf(xr[f0 + 2]) : 0;
    o.w = (f0 + 3 < 100) ? f2bf(xr[f0 + 3]) : 0;
    *(ushort4*)(xp + (size_t)node * 128 + f0) = o;
}

// ---------------------------------------------------------------- CSR build
__global__ void count_k(const int* __restrict__ dst, int* __restrict__ counts, int E) {
    int i = blockIdx.x * blockDim.x + threadIdx.x;
    if (i < E) atomicAdd(&counts[dst[i]], 1);
}

__global__ void scan1(const int* __restrict__ counts, int* __restrict__ rp,
                      int* __restrict__ partials, int n) {
    __shared__ int s[256];
    int t = threadIdx.x;
    int i = blockIdx.x * 256 + t;
    int v = (i < n) ? counts[i] : 0;
    s[t] = v;
    __syncthreads();
    for (int off = 1; off < 256; off <<= 1) {
        int u = (t >= off) ? s[t - off] : 0;
        __syncthreads();
        s[t] += u;
        __syncthreads();
    }
    if (i < n) rp[i] = s[t] - v;
    if (t == 255) partials[blockIdx.x] = s[255];
}

__global__ void scan2(int* __restrict__ partials, int nb) {
    __shared__ int s[512];
    int t = threadIdx.x;
    int v = (t < nb) ? partials[t] : 0;
    s[t] = v;
    __syncthreads();
    for (int off = 1; off < 512; off <<= 1) {
        int u = (t >= off) ? s[t - off] : 0;
        __syncthreads();
        s[t] += u;
        __syncthreads();
    }
    if (t < nb) partials[t] = s[t] - v;
}

__global__ void scan3(int* __restrict__ rp, const int* __restrict__ partials, int n, int E) {
    int i = blockIdx.x * blockDim.x + threadIdx.x;
    if (i < n) rp[i] += partials[i >> 8];
    if (i == 0) rp[n] = E;
}

__global__ void fill_k(const int* __restrict__ src, const int* __restrict__ dst,
                       const int* __restrict__ rp, int* __restrict__ cursor,
                       int* __restrict__ col, int E) {
    int i = blockIdx.x * blockDim.x + threadIdx.x;
    if (i < E) {
        int d = dst[i];
        int pos = atomicAdd(&cursor[d], 1);
        col[rp[d] + pos] = src[i];
    }
}

// ------------------------------------------------------- gather aggregation
__global__ __launch_bounds__(256) void agg_bf16_256(
    const unsigned short* __restrict__ x, const int* __restrict__ rp,
    const int* __restrict__ col, unsigned short* __restrict__ out, int n) {
    int wave = threadIdx.x >> 6, lane = threadIdx.x & 63;
    int node = blockIdx.x * 4 + wave;
    if (node >= n) return;
    int s = rp[node], e = rp[node + 1];
    int deg = e - s;
    int h = lane >> 5;
    int l32 = lane & 31;

    float a[8] = {0, 0, 0, 0, 0, 0, 0, 0};
    int base = 0;
    for (; base + 8 <= deg; base += 8) {
        int i = s + base + h;
        int r0 = col[i], r1 = col[i + 2], r2 = col[i + 4], r3 = col[i + 6];
        ushort8 v0 = *(const ushort8*)(x + (size_t)r0 * 256 + l32 * 8);
        ushort8 v1 = *(const ushort8*)(x + (size_t)r1 * 256 + l32 * 8);
        ushort8 v2 = *(const ushort8*)(x + (size_t)r2 * 256 + l32 * 8);
        ushort8 v3 = *(const ushort8*)(x + (size_t)r3 * 256 + l32 * 8);
#pragma unroll
        for (int j = 0; j < 8; ++j)
            a[j] += bf2f(v0[j]) + bf2f(v1[j]) + bf2f(v2[j]) + bf2f(v3[j]);
    }
    for (int i = s + base + h; i < e; i += 2) {
        int r = col[i];
        ushort8 v = *(const ushort8*)(x + (size_t)r * 256 + l32 * 8);
#pragma unroll
        for (int j = 0; j < 8; ++j) a[j] += bf2f(v[j]);
    }
#pragma unroll
    for (int j = 0; j < 8; ++j) a[j] += __shfl_xor(a[j], 32);

    if (h == 0) {
        float sc = 1.0f / fmaxf((float)deg, 1.0f);
        ushort8 o;
#pragma unroll
        for (int j = 0; j < 8; ++j) o[j] = f2bf(a[j] * sc);
        *(ushort8*)(out + (size_t)node * 256 + l32 * 8) = o;
    }
}

__global__ __launch_bounds__(256) void agg_bf16_128(
    const unsigned short* __restrict__ x, const int* __restrict__ rp,
    const int* __restrict__ col, unsigned short* __restrict__ out, int n) {
    int wave = threadIdx.x >> 6, lane = threadIdx.x & 63;
    int node = blockIdx.x * 4 + wave;
    if (node >= n) return;
    int s = rp[node], e = rp[node + 1];
    int deg = e - s;
    int q = lane >> 4;
    int l16 = lane & 15;

    float a[8] = {0, 0, 0, 0, 0, 0, 0, 0};
    int base = 0;
    for (; base + 16 <= deg; base += 16) {
        int i = s + base + q;
        int r0 = col[i], r1 = col[i + 4], r2 = col[i + 8], r3 = col[i + 12];
        ushort8 v0 = *(const ushort8*)(x + (size_t)r0 * 128 + l16 * 8);
        ushort8 v1 = *(const ushort8*)(x + (size_t)r1 * 128 + l16 * 8);
        ushort8 v2 = *(const ushort8*)(x + (size_t)r2 * 128 + l16 * 8);
        ushort8 v3 = *(const ushort8*)(x + (size_t)r3 * 128 + l16 * 8);
#pragma unroll
        for (int j = 0; j < 8; ++j)
            a[j] += bf2f(v0[j]) + bf2f(v1[j]) + bf2f(v2[j]) + bf2f(v3[j]);
    }
    for (int i = s + base + q; i < e; i += 4) {
        int r = col[i];
        ushort8 v = *(const ushort8*)(x + (size_t)r * 128 + l16 * 8);
#pragma unroll
        for (int j = 0; j < 8; ++j) a[j] += bf2f(v[j]);
    }
#pragma unroll
    for (int j = 0; j < 8; ++j) {
        a[j] += __shfl_xor(a[j], 16);
        a[j] += __shfl_xor(a[j], 32);
    }

    if (lane < 16) {
        float sc = 1.0f / fmaxf((float)deg, 1.0f);
        ushort8 o;
#pragma unroll
        for (int j = 0; j < 8; ++j) o[j] = f2bf(a[j] * sc);
        *(ushort8*)(out + (size_t)node * 128 + l16 * 8) = o;
    }
}

// ------------------------------------------------- fused SAGE linear (MFMA)
// m97-style: 128x128 block tile, 256 threads = 4 waves (2Mx2N), each wave a
// 64x64 quadrant (4x4 16x16 tiles). A ([x|agg]) and B ([Wr|Wl]) panels staged
// per 32-K step into LDS in MFMA fragment order via global_load_lds(16B);
// 2 barriers per k-step; ds_read:MFMA = 1:2.
// Grid: (ceil(n/128), DOUT/128).
template <int KTOT, int DOUT, bool HAS_AGG, bool RELU, bool STF32, bool STBF16>
__global__ __launch_bounds__(256) void sage_mfma(
    const unsigned short* __restrict__ xp, const unsigned short* __restrict__ ap,
    const unsigned short* __restrict__ Wr, const unsigned short* __restrict__ Wl,
    const float* __restrict__ bias,
    float* __restrict__ outf, unsigned short* __restrict__ outb, int n) {
    constexpr int NSRC = HAS_AGG ? 2 : 1;
    constexpr int NCHUNK = NSRC * 16;       // 1KB chunks per k-step (A + B panels)
    constexpr int CPW = NCHUNK / 4;         // chunks staged per wave (8 or 4)
    constexpr int KS = KTOT / 32;
    __shared__ __align__(16) unsigned short lds[NCHUNK * 512];

    const int t = threadIdx.x;
    const int wave = t >> 6, lane = t & 63;
    const int wm = wave >> 1, wn = wave & 1;
    const int lcol = lane & 15, lq = lane >> 4;
    const int node_base = blockIdx.x * 128;
    const int col_base = blockIdx.y * 128;

    // ---- per-wave staging panel (each wave stages chunks [wave*CPW, +CPW),
    // which all belong to ONE panel). Panel order: A_x, (A_agg), B_r, (B_l).
    const int p_w = HAS_AGG ? wave : (wave >> 1);
    const int tile0 = HAS_AGG ? 0 : (wave & 1) * 4;
    const unsigned short* gpan;
    int growbase;
    if constexpr (HAS_AGG) {
        gpan = (p_w == 0) ? xp : (p_w == 1) ? ap : (p_w == 2) ? Wr : Wl;
        growbase = (p_w < 2) ? node_base : col_base;
    } else {
        gpan = (p_w == 0) ? xp : Wr;
        growbase = (p_w == 0) ? node_base : col_base;
    }
    const unsigned short* gbase =
        gpan + (size_t)(growbase + tile0 * 16 + lcol) * KTOT + lq * 8;
    const int cbase = (p_w * 8 + tile0) * 512;   // LDS ushort offset of first chunk

    f32x4 acc[4][4];
#pragma unroll
    for (int ct = 0; ct < 4; ++ct) {
        float b = bias[col_base + wn * 64 + ct * 16 + lcol];
#pragma unroll
        for (int mt = 0; mt < 4; ++mt) {
            acc[mt][ct][0] = b; acc[mt][ct][1] = b; acc[mt][ct][2] = b; acc[mt][ct][3] = b;
        }
    }

    for (int ks = 0; ks < KS; ++ks) {
        // stage this k-step's panels (8 global_load_lds x 16B per wave)
#pragma unroll
        for (int i = 0; i < CPW; ++i) {
            const unsigned short* g = gbase + (size_t)i * 16 * KTOT + ks * 32;
            __builtin_amdgcn_global_load_lds((gas_ptr)g, (las_ptr)(lds + cbase + i * 512),
                                             16, 0, 0);
        }
        __syncthreads();   // drains vmcnt -> panels visible
#pragma unroll
        for (int s = 0; s < NSRC; ++s) {
            short8 af[4], bf[4];
#pragma unroll
            for (int i = 0; i < 4; ++i) {
                af[i] = *(const short8*)(lds + (s * 8 + wm * 4 + i) * 512 + lane * 8);
                bf[i] = *(const short8*)(lds + ((NSRC + s) * 8 + wn * 4 + i) * 512 + lane * 8);
            }
#pragma unroll
            for (int mt = 0; mt < 4; ++mt)
#pragma unroll
                for (int ct = 0; ct < 4; ++ct)
                    acc[mt][ct] = __builtin_amdgcn_mfma_f32_16x16x32_bf16(
                        af[mt], bf[ct], acc[mt][ct], 0, 0, 0);
        }
        __syncthreads();   // before next stage overwrites
    }

#pragma unroll
    for (int mt = 0; mt < 4; ++mt) {
        int row0 = node_base + wm * 64 + mt * 16 + lq * 4;
        if (row0 >= n) continue;
#pragma unroll
        for (int ct = 0; ct < 4; ++ct) {
            f32x4 v = acc[mt][ct];
            if (RELU) {
                v[0] = fmaxf(v[0], 0.0f); v[1] = fmaxf(v[1], 0.0f);
                v[2] = fmaxf(v[2], 0.0f); v[3] = fmaxf(v[3], 0.0f);
            }
            int colI = col_base + wn * 64 + ct * 16 + lcol;
#pragma unroll
            for (int j = 0; j < 4; ++j) {
                int row = row0 + j;
                if (row < n) {
                    if (STF32) outf[(size_t)row * DOUT + colI] = v[j];
                    if (STBF16) outb[(size_t)row * DOUT + colI] = f2bf(v[j]);
                }
            }
        }
    }
}

// ---------------------------------------------------------------- BatchNorm
__global__ void bn_partial(const float* __restrict__ z, float* __restrict__ sums, int n) {
    int f = threadIdx.x & 127;
    int half = threadIdx.x >> 7;
    float s = 0.0f, s2 = 0.0f;
    for (int row = blockIdx.x * 2 + half; row < n; row += gridDim.x * 2) {
        float v = z[(size_t)row * 128 + f];
        s += v; s2 += v * v;
    }
    __shared__ float ls[256], ls2[256];
    ls[threadIdx.x] = s; ls2[threadIdx.x] = s2;
    __syncthreads();
    if (half == 0) {
        atomicAdd(&sums[f], s + ls[128 + f]);
        atomicAdd(&sums[128 + f], s2 + ls2[128 + f]);
    }
}

__global__ void bn_finalize(const float* __restrict__ sums, const float* __restrict__ gamma,
                            const float* __restrict__ beta, float* __restrict__ params, int n) {
    int f = threadIdx.x;  // 128 threads
    float mu = sums[f] / (float)n;
    float var = sums[128 + f] / (float)n - mu * mu;
    float inv = rsqrtf(var + EPS_BN);
    float sc = gamma[f] * inv;
    params[f] = sc;
    params[128 + f] = beta[f] - mu * sc;
}

__global__ void bn_apply(float* __restrict__ z, const float* __restrict__ params, int total4) {
    int i = blockIdx.x * blockDim.x + threadIdx.x;
    for (; i < total4; i += gridDim.x * blockDim.x) {
        float4 v = ((float4*)z)[i];
        int f0 = (i & 31) * 4;
        v.x = v.x * params[f0 + 0] + params[128 + f0 + 0];
        v.y = v.y * params[f0 + 1] + params[128 + f0 + 1];
        v.z = v.z * params[f0 + 2] + params[128 + f0 + 2];
        v.w = v.w * params[f0 + 3] + params[128 + f0 + 3];
        ((float4*)z)[i] = v;
    }
}

// ---------------------------------------------------------------- launcher
extern "C" void kernel_launch(void* const* d_in, const int* in_sizes, int n_in,
                              void* d_out, int out_size, void* d_ws, size_t ws_size,
                              hipStream_t stream) {
    const float* x_in  = (const float*)d_in[0];
    const int*   ei    = (const int*)d_in[1];
    const float* Wl0   = (const float*)d_in[2];
    const float* bl0   = (const float*)d_in[3];
    const float* Wr0   = (const float*)d_in[4];
    const float* Wl1   = (const float*)d_in[5];
    const float* bl1   = (const float*)d_in[6];
    const float* Wr1   = (const float*)d_in[7];
    const float* Wl2   = (const float*)d_in[8];
    const float* bl2   = (const float*)d_in[9];
    const float* Wr2   = (const float*)d_in[10];
    const float* Wp    = (const float*)d_in[11];
    const float* bp    = (const float*)d_in[12];
    const float* gamma = (const float*)d_in[13];
    const float* beta  = (const float*)d_in[14];

    const int IN = 100, INP = 128, H = 256, OUT = 256, P = 128;
    const int n = in_sizes[0] / IN;          // 100000
    const int E = in_sizes[1] / 2;           // 1600000
    const int* src = ei;
    const int* dst = ei + E;

    size_t off = 0;
    auto alloc = [&](size_t bytes) -> char* {
        char* p = (char*)d_ws + off;
        off += (bytes + 255) & ~(size_t)255;
        return p;
    };
    int*   counts   = (int*)alloc((size_t)n * 4);
    int*   cursor   = (int*)alloc((size_t)n * 4);
    int*   rp       = (int*)alloc((size_t)(n + 1) * 4);
    int*   partials = (int*)alloc(512 * 4);
    int*   col      = (int*)alloc((size_t)E * 4);
    unsigned short* Wl0b = (unsigned short*)alloc((size_t)H * INP * 2);
    unsigned short* Wr0b = (unsigned short*)alloc((size_t)H * INP * 2);
    unsigned short* Wl1b = (unsigned short*)alloc((size_t)H * H * 2);
    unsigned short* Wr1b = (unsigned short*)alloc((size_t)H * H * 2);
    unsigned short* Wl2b = (unsigned short*)alloc((size_t)OUT * H * 2);
    unsigned short* Wr2b = (unsigned short*)alloc((size_t)OUT * H * 2);
    unsigned short* Wpb  = (unsigned short*)alloc((size_t)P * OUT * 2);
    float* bnsums   = (float*)alloc(256 * 4);
    float* bnparams = (float*)alloc(256 * 4);
    unsigned short* bufA = (unsigned short*)alloc((size_t)n * H * 2);
    unsigned short* bufB = (unsigned short*)alloc((size_t)n * H * 2);
    unsigned short* bufC = (unsigned short*)alloc((size_t)n * H * 2);
    unsigned short* bufD = (unsigned short*)alloc((size_t)n * H * 2);
    (void)alloc((size_t)256 * 512);                      // OOB guard for last-tile reads

    unsigned short* xpad   = bufA;                        // [n][128]
    unsigned short* aggpad = bufA + (size_t)n * INP;      // [n][128]
    unsigned short* h1b  = bufB;
    unsigned short* agg1 = bufC;
    unsigned short* h2b  = bufD;
    unsigned short* agg2 = bufB;                          // reuse (h1 dead)
    unsigned short* xb2  = bufA;                          // reuse (xpad/aggpad dead)

    float* out_x = (float*)d_out;                  // [n][256] final x
    float* z     = out_x + (size_t)n * OUT;        // [n][128] projection/BN output

    const int nb = (n + 255) / 256;
    const int gx = (n + 127) / 128;

    // --- CSR build ---
    zero_i32<<<nb, 256, 0, stream>>>(counts, n);
    zero_i32<<<nb, 256, 0, stream>>>(cursor, n);
    zero_f32<<<1, 256, 0, stream>>>(bnsums, 256);
    count_k<<<(E + 255) / 256, 256, 0, stream>>>(dst, counts, E);
    scan1<<<nb, 256, 0, stream>>>(counts, rp, partials, n);
    scan2<<<1, 512, 0, stream>>>(partials, nb);
    scan3<<<nb, 256, 0, stream>>>(rp, partials, n, E);
    fill_k<<<(E + 255) / 256, 256, 0, stream>>>(src, dst, rp, cursor, col, E);

    // --- dtype conversions ---
    conv_x_pad<<<(n * 32 + 255) / 256, 256, 0, stream>>>(x_in, xpad, n);
    conv_w<<<(H * INP + 255) / 256, 256, 0, stream>>>(Wl0, Wl0b, H, IN, INP);
    conv_w<<<(H * INP + 255) / 256, 256, 0, stream>>>(Wr0, Wr0b, H, IN, INP);
    conv_w<<<(H * H + 255) / 256, 256, 0, stream>>>(Wl1, Wl1b, H, H, H);
    conv_w<<<(H * H + 255) / 256, 256, 0, stream>>>(Wr1, Wr1b, H, H, H);
    conv_w<<<(OUT * H + 255) / 256, 256, 0, stream>>>(Wl2, Wl2b, OUT, H, H);
    conv_w<<<(OUT * H + 255) / 256, 256, 0, stream>>>(Wr2, Wr2b, OUT, H, H);
    conv_w<<<(P * OUT + 255) / 256, 256, 0, stream>>>(Wp, Wpb, P, OUT, OUT);

    // --- layer 0: 128(pad) -> 256, relu ---
    agg_bf16_128<<<(n + 3) / 4, 256, 0, stream>>>(xpad, rp, col, aggpad, n);
    sage_mfma<128, 256, true, true, false, true><<<dim3(gx, 2), 256, 0, stream>>>(
        xpad, aggpad, Wr0b, Wl0b, bl0, nullptr, h1b, n);

    // --- layer 1: 256 -> 256, relu ---
    agg_bf16_256<<<(n + 3) / 4, 256, 0, stream>>>(h1b, rp, col, agg1, n);
    sage_mfma<256, 256, true, true, false, true><<<dim3(gx, 2), 256, 0, stream>>>(
        h1b, agg1, Wr1b, Wl1b, bl1, nullptr, h2b, n);

    // --- layer 2: 256 -> 256, no relu; f32 -> d_out, bf16 copy for projection ---
    agg_bf16_256<<<(n + 3) / 4, 256, 0, stream>>>(h2b, rp, col, agg2, n);
    sage_mfma<256, 256, true, false, true, true><<<dim3(gx, 2), 256, 0, stream>>>(
        h2b, agg2, Wr2b, Wl2b, bl2, out_x, xb2, n);

    // --- projection head: 256 -> 128 ---
    sage_mfma<256, 128, false, false, true, false><<<dim3(gx, 1), 256, 0, stream>>>(
        xb2, nullptr, Wpb, nullptr, bp, z, nullptr, n);

    // --- BatchNorm over z ---
    bn_partial<<<256, 256, 0, stream>>>(z, bnsums, n);
    bn_finalize<<<1, 128, 0, stream>>>(bnsums, gamma, beta, bnparams, n);
    bn_apply<<<2048, 256, 0, stream>>>(z, bnparams, n * (P / 4));
}

// Round 7
// 746.638 us; speedup vs baseline: 1.2226x; 1.0273x over previous
//
#include <hip/hip_runtime.h>
#include <hip/hip_bf16.h>

#define EPS_BN 1e-5f

using short8  = __attribute__((ext_vector_type(8))) short;
using ushort8 = __attribute__((ext_vector_type(8))) unsigned short;
using f32x4   = __attribute__((ext_vector_type(4))) float;

typedef const __attribute__((address_space(1))) void* gas_ptr;
typedef __attribute__((address_space(3))) void* las_ptr;

__device__ inline float bf2f(unsigned short u) {
    union { unsigned i; float f; } c; c.i = ((unsigned)u) << 16; return c.f;
}
__device__ inline unsigned short f2bf(float f) {
    unsigned x = __float_as_uint(f);
    unsigned r = (x + 0x7FFF + ((x >> 16) & 1)) >> 16;   // RNE
    return (unsigned short)r;
}

// ---------------------------------------------------------------- utilities
__global__ void zero_i32(int* __restrict__ p, int n) {
    int i = blockIdx.x * blockDim.x + threadIdx.x;
    if (i < n) p[i] = 0;
}
__global__ void zero_f32(float* __restrict__ p, int n) {
    int i = blockIdx.x * blockDim.x + threadIdx.x;
    if (i < n) p[i] = 0.0f;
}

// zero row n of the three gathered tables (pad target)
__global__ void zero_rows(unsigned short* __restrict__ xpad,
                          unsigned short* __restrict__ h1,
                          unsigned short* __restrict__ h2, int n) {
    int t = threadIdx.x;  // 256
    if (t < 128) xpad[(size_t)n * 128 + t] = 0;
    h1[(size_t)n * 256 + t] = 0;
    h2[(size_t)n * 256 + t] = 0;
}

// fp32 [R][C] -> bf16 [R][CP], zero-padded columns
__global__ void conv_w(const float* __restrict__ w, unsigned short* __restrict__ o,
                       int R, int C, int CP) {
    int t = blockIdx.x * blockDim.x + threadIdx.x;
    if (t >= R * CP) return;
    int r = t / CP, c = t % CP;
    o[t] = (c < C) ? f2bf(w[(size_t)r * C + c]) : (unsigned short)0;
}

// x [n][100] f32 -> xpad [n][128] bf16 (zero pad)
__global__ void conv_x_pad(const float* __restrict__ x, unsigned short* __restrict__ xp, int n) {
    int t = blockIdx.x * blockDim.x + threadIdx.x;
    if (t >= n * 32) return;
    int node = t >> 5, g = t & 31;
    int f0 = g * 4;
    ushort4 o;
    const float* xr = x + (size_t)node * 100;
    o.x = (f0 + 0 < 100) ? f2bf(xr[f0 + 0]) : 0;
    o.y = (f0 + 1 < 100) ? f2bf(xr[f0 + 1]) : 0;
    o.z = (f0 + 2 < 100) ? f2bf(xr[f0 + 2]) : 0;
    o.w = (f0 + 3 < 100) ? f2bf(xr[f0 + 3]) : 0;
    *(ushort4*)(xp + (size_t)node * 128 + f0) = o;
}

// ---------------------------------------------------------------- CSR build
__global__ void count_k(const int* __restrict__ dst, int* __restrict__ counts, int E) {
    int i = blockIdx.x * blockDim.x + threadIdx.x;
    if (i < E) atomicAdd(&counts[dst[i]], 1);
}

// exclusive scan of PADDED counts (pad each node's list to a multiple of 8)
__global__ void scan1(const int* __restrict__ counts, int* __restrict__ rp,
                      int* __restrict__ partials, int n) {
    __shared__ int s[256];
    int t = threadIdx.x;
    int i = blockIdx.x * 256 + t;
    int v = (i < n) ? ((counts[i] + 7) & ~7) : 0;
    s[t] = v;
    __syncthreads();
    for (int off = 1; off < 256; off <<= 1) {
        int u = (t >= off) ? s[t - off] : 0;
        __syncthreads();
        s[t] += u;
        __syncthreads();
    }
    if (i < n) rp[i] = s[t] - v;
    if (t == 255) partials[blockIdx.x] = s[255];
}

__global__ void scan2(int* __restrict__ partials, int nb) {
    __shared__ int s[512];
    int t = threadIdx.x;
    int v = (t < nb) ? partials[t] : 0;
    s[t] = v;
    __syncthreads();
    for (int off = 1; off < 512; off <<= 1) {
        int u = (t >= off) ? s[t - off] : 0;
        __syncthreads();
        s[t] += u;
        __syncthreads();
    }
    if (t < nb) partials[t] = s[t] - v;
}

__global__ void scan3(int* __restrict__ rp, const int* __restrict__ partials, int n) {
    int i = blockIdx.x * blockDim.x + threadIdx.x;
    if (i < n) rp[i] += partials[i >> 8];
}

__global__ void fill_k(const int* __restrict__ src, const int* __restrict__ dst,
                       const int* __restrict__ rp, int* __restrict__ cursor,
                       int* __restrict__ col, int E) {
    int i = blockIdx.x * blockDim.x + threadIdx.x;
    if (i < E) {
        int d = dst[i];
        int pos = atomicAdd(&cursor[d], 1);
        col[rp[d] + pos] = src[i];
    }
}

// write zero-row index into pad slots [deg, deg8)
__global__ void pad_fill(const int* __restrict__ rp, const int* __restrict__ cnt,
                         int* __restrict__ col, int n, int zrow) {
    int node = blockIdx.x * blockDim.x + threadIdx.x;
    if (node >= n) return;
    int d = cnt[node];
    int s = rp[node] + d;
    int e = rp[node] + ((d + 7) & ~7);
    for (int i = s; i < e; ++i) col[i] = zrow;
}

// ------------------------------------------------------- gather aggregation
// D=256: one wave per node; halves (32 lanes x 16B) cover a full row, h picks
// neighbor parity. Padded CSR (multiple of 8, pad -> zero row): branch-free
// batches of 8 neighbors; main loop does 2 batches/trip = 8 gathers in flight.
__global__ __launch_bounds__(256) void agg_bf16_256(
    const unsigned short* __restrict__ x, const int* __restrict__ rp,
    const int* __restrict__ cnt, const int* __restrict__ col,
    unsigned short* __restrict__ out, int n) {
    int wave = threadIdx.x >> 6, lane = threadIdx.x & 63;
    int node = blockIdx.x * 4 + wave;
    if (node >= n) return;
    int s = rp[node];
    int deg = cnt[node];
    int nb8 = (deg + 7) >> 3;
    int h = lane >> 5;
    int l32 = lane & 31;
    const size_t coff = (size_t)l32 * 8;

    float a[8] = {0, 0, 0, 0, 0, 0, 0, 0};
    int i = s + h;
    int b = 0;
    for (; b + 2 <= nb8; b += 2, i += 16) {
        int r0 = col[i],     r1 = col[i + 2],  r2 = col[i + 4],  r3 = col[i + 6];
        int r4 = col[i + 8], r5 = col[i + 10], r6 = col[i + 12], r7 = col[i + 14];
        ushort8 v0 = *(const ushort8*)(x + (size_t)r0 * 256 + coff);
        ushort8 v1 = *(const ushort8*)(x + (size_t)r1 * 256 + coff);
        ushort8 v2 = *(const ushort8*)(x + (size_t)r2 * 256 + coff);
        ushort8 v3 = *(const ushort8*)(x + (size_t)r3 * 256 + coff);
        ushort8 v4 = *(const ushort8*)(x + (size_t)r4 * 256 + coff);
        ushort8 v5 = *(const ushort8*)(x + (size_t)r5 * 256 + coff);
        ushort8 v6 = *(const ushort8*)(x + (size_t)r6 * 256 + coff);
        ushort8 v7 = *(const ushort8*)(x + (size_t)r7 * 256 + coff);
#pragma unroll
        for (int j = 0; j < 8; ++j)
            a[j] += ((bf2f(v0[j]) + bf2f(v1[j])) + (bf2f(v2[j]) + bf2f(v3[j]))) +
                    ((bf2f(v4[j]) + bf2f(v5[j])) + (bf2f(v6[j]) + bf2f(v7[j])));
    }
    if (b < nb8) {
        int r0 = col[i], r1 = col[i + 2], r2 = col[i + 4], r3 = col[i + 6];
        ushort8 v0 = *(const ushort8*)(x + (size_t)r0 * 256 + coff);
        ushort8 v1 = *(const ushort8*)(x + (size_t)r1 * 256 + coff);
        ushort8 v2 = *(const ushort8*)(x + (size_t)r2 * 256 + coff);
        ushort8 v3 = *(const ushort8*)(x + (size_t)r3 * 256 + coff);
#pragma unroll
        for (int j = 0; j < 8; ++j)
            a[j] += (bf2f(v0[j]) + bf2f(v1[j])) + (bf2f(v2[j]) + bf2f(v3[j]));
    }
#pragma unroll
    for (int j = 0; j < 8; ++j) a[j] += __shfl_xor(a[j], 32);

    if (h == 0) {
        float sc = 1.0f / fmaxf((float)deg, 1.0f);
        ushort8 o;
#pragma unroll
        for (int j = 0; j < 8; ++j) o[j] = f2bf(a[j] * sc);
        *(ushort8*)(out + (size_t)node * 256 + l32 * 8) = o;
    }
}

// D=128: quarters (16 lanes x 16B) cover a row; q picks neighbor within 4.
// Batch of 8 = 2 loads; main loop 2 batches/trip = 4 gathers in flight.
__global__ __launch_bounds__(256) void agg_bf16_128(
    const unsigned short* __restrict__ x, const int* __restrict__ rp,
    const int* __restrict__ cnt, const int* __restrict__ col,
    unsigned short* __restrict__ out, int n) {
    int wave = threadIdx.x >> 6, lane = threadIdx.x & 63;
    int node = blockIdx.x * 4 + wave;
    if (node >= n) return;
    int s = rp[node];
    int deg = cnt[node];
    int nb8 = (deg + 7) >> 3;
    int q = lane >> 4;
    int l16 = lane & 15;
    const size_t coff = (size_t)l16 * 8;

    float a[8] = {0, 0, 0, 0, 0, 0, 0, 0};
    int i = s + q;
    int b = 0;
    for (; b + 2 <= nb8; b += 2, i += 16) {
        int r0 = col[i], r1 = col[i + 4], r2 = col[i + 8], r3 = col[i + 12];
        ushort8 v0 = *(const ushort8*)(x + (size_t)r0 * 128 + coff);
        ushort8 v1 = *(const ushort8*)(x + (size_t)r1 * 128 + coff);
        ushort8 v2 = *(const ushort8*)(x + (size_t)r2 * 128 + coff);
        ushort8 v3 = *(const ushort8*)(x + (size_t)r3 * 128 + coff);
#pragma unroll
        for (int j = 0; j < 8; ++j)
            a[j] += (bf2f(v0[j]) + bf2f(v1[j])) + (bf2f(v2[j]) + bf2f(v3[j]));
    }
    if (b < nb8) {
        int r0 = col[i], r1 = col[i + 4];
        ushort8 v0 = *(const ushort8*)(x + (size_t)r0 * 128 + coff);
        ushort8 v1 = *(const ushort8*)(x + (size_t)r1 * 128 + coff);
#pragma unroll
        for (int j = 0; j < 8; ++j) a[j] += bf2f(v0[j]) + bf2f(v1[j]);
    }
#pragma unroll
    for (int j = 0; j < 8; ++j) {
        a[j] += __shfl_xor(a[j], 16);
        a[j] += __shfl_xor(a[j], 32);
    }

    if (lane < 16) {
        float sc = 1.0f / fmaxf((float)deg, 1.0f);
        ushort8 o;
#pragma unroll
        for (int j = 0; j < 8; ++j) o[j] = f2bf(a[j] * sc);
        *(ushort8*)(out + (size_t)node * 128 + l16 * 8) = o;
    }
}

// ------------------------------------------------- fused SAGE linear (MFMA)
// R3 structure (measured best): 512 threads = 8 waves; 128 nodes/block
// (wave w -> 16 nodes), full DOUT cols per wave. W fragments staged via
// global_load_lds (16B, lane-linear), double-buffered, ONE barrier per
// k-step: stage(ks+1) issued before compute(ks).
template <int KTOT, int DOUT, bool HAS_AGG, bool RELU, bool STF32, bool STBF16>
__global__ __launch_bounds__(512) void sage_mfma(
    const unsigned short* __restrict__ xp, const unsigned short* __restrict__ ap,
    const unsigned short* __restrict__ Wr, const unsigned short* __restrict__ Wl,
    const float* __restrict__ bias,
    float* __restrict__ outf, unsigned short* __restrict__ outb, int n) {
    constexpr int CT = DOUT / 16;
    constexpr int NSRC = HAS_AGG ? 2 : 1;
    constexpr int FR = DOUT * 4;           // 16B frags per src per kstep
    constexpr int CHUNKS = NSRC * CT;      // 1KB chunks per kstep
    constexpr int CPW = CHUNKS / 8;
    constexpr int KS = KTOT / 32;
    constexpr int BUFSZ = NSRC * FR * 8;   // ushorts per buffer
    __shared__ __align__(16) unsigned short lds[2 * BUFSZ];

    const int t = threadIdx.x;
    const int wave = t >> 6, lane = t & 63;
    const int node0 = blockIdx.x * 128 + wave * 16;
    const bool active = node0 < n;
    const int lcol = lane & 15, lq = lane >> 4;

    auto stage = [&](int ks, int buf) {
        unsigned short* base = lds + buf * BUFSZ;
#pragma unroll
        for (int i = 0; i < CPW; ++i) {
            int chunk = wave * CPW + i;
            int srcSel = chunk / CT, ct = chunk % CT;
            const unsigned short* W = (srcSel == 0) ? Wr : Wl;
            const unsigned short* g = W + (size_t)(ct * 16 + lcol) * KTOT + ks * 32 + lq * 8;
            unsigned short* l = base + chunk * 512;
            __builtin_amdgcn_global_load_lds((gas_ptr)g, (las_ptr)l, 16, 0, 0);
        }
    };

    f32x4 acc[CT];
#pragma unroll
    for (int c = 0; c < CT; ++c) {
        float b = bias[c * 16 + lcol];
        acc[c][0] = b; acc[c][1] = b; acc[c][2] = b; acc[c][3] = b;
    }

    const unsigned short* aRow  = xp + (size_t)(node0 + lcol) * KTOT + lq * 8;
    const unsigned short* aRow2 = HAS_AGG ? (ap + (size_t)(node0 + lcol) * KTOT + lq * 8) : xp;

    stage(0, 0);
    __syncthreads();

    for (int ks = 0; ks < KS; ++ks) {
        if (ks + 1 < KS) stage(ks + 1, (ks + 1) & 1);
        if (active) {
            short8 a = *(const short8*)(aRow + ks * 32);
            const short8* bf = (const short8*)(lds + (ks & 1) * BUFSZ);
#pragma unroll
            for (int c = 0; c < CT; ++c)
                acc[c] = __builtin_amdgcn_mfma_f32_16x16x32_bf16(a, bf[c * 64 + lane], acc[c], 0, 0, 0);
            if (HAS_AGG) {
                short8 a2 = *(const short8*)(aRow2 + ks * 32);
                const short8* bf2 = bf + FR;
#pragma unroll
                for (int c = 0; c < CT; ++c)
                    acc[c] = __builtin_amdgcn_mfma_f32_16x16x32_bf16(a2, bf2[c * 64 + lane], acc[c], 0, 0, 0);
            }
        }
        __syncthreads();
    }
    if (!active) return;

#pragma unroll
    for (int c = 0; c < CT; ++c) {
        f32x4 v = acc[c];
        if (RELU) {
            v[0] = fmaxf(v[0], 0.0f); v[1] = fmaxf(v[1], 0.0f);
            v[2] = fmaxf(v[2], 0.0f); v[3] = fmaxf(v[3], 0.0f);
        }
#pragma unroll
        for (int j = 0; j < 4; ++j) {
            size_t row = (size_t)node0 + lq * 4 + j;
            int colI = c * 16 + lcol;
            if (STF32) outf[row * DOUT + colI] = v[j];
            if (STBF16) outb[row * DOUT + colI] = f2bf(v[j]);
        }
    }
}

// ---------------------------------------------------------------- BatchNorm
__global__ void bn_partial(const float* __restrict__ z, float* __restrict__ sums, int n) {
    int f = threadIdx.x & 127;
    int half = threadIdx.x >> 7;
    float s = 0.0f, s2 = 0.0f;
    for (int row = blockIdx.x * 2 + half; row < n; row += gridDim.x * 2) {
        float v = z[(size_t)row * 128 + f];
        s += v; s2 += v * v;
    }
    __shared__ float ls[256], ls2[256];
    ls[threadIdx.x] = s; ls2[threadIdx.x] = s2;
    __syncthreads();
    if (half == 0) {
        atomicAdd(&sums[f], s + ls[128 + f]);
        atomicAdd(&sums[128 + f], s2 + ls2[128 + f]);
    }
}

__global__ void bn_finalize(const float* __restrict__ sums, const float* __restrict__ gamma,
                            const float* __restrict__ beta, float* __restrict__ params, int n) {
    int f = threadIdx.x;  // 128 threads
    float mu = sums[f] / (float)n;
    float var = sums[128 + f] / (float)n - mu * mu;
    float inv = rsqrtf(var + EPS_BN);
    float sc = gamma[f] * inv;
    params[f] = sc;
    params[128 + f] = beta[f] - mu * sc;
}

__global__ void bn_apply(float* __restrict__ z, const float* __restrict__ params, int total4) {
    int i = blockIdx.x * blockDim.x + threadIdx.x;
    for (; i < total4; i += gridDim.x * blockDim.x) {
        float4 v = ((float4*)z)[i];
        int f0 = (i & 31) * 4;
        v.x = v.x * params[f0 + 0] + params[128 + f0 + 0];
        v.y = v.y * params[f0 + 1] + params[128 + f0 + 1];
        v.z = v.z * params[f0 + 2] + params[128 + f0 + 2];
        v.w = v.w * params[f0 + 3] + params[128 + f0 + 3];
        ((float4*)z)[i] = v;
    }
}

// ---------------------------------------------------------------- launcher
extern "C" void kernel_launch(void* const* d_in, const int* in_sizes, int n_in,
                              void* d_out, int out_size, void* d_ws, size_t ws_size,
                              hipStream_t stream) {
    const float* x_in  = (const float*)d_in[0];
    const int*   ei    = (const int*)d_in[1];
    const float* Wl0   = (const float*)d_in[2];
    const float* bl0   = (const float*)d_in[3];
    const float* Wr0   = (const float*)d_in[4];
    const float* Wl1   = (const float*)d_in[5];
    const float* bl1   = (const float*)d_in[6];
    const float* Wr1   = (const float*)d_in[7];
    const float* Wl2   = (const float*)d_in[8];
    const float* bl2   = (const float*)d_in[9];
    const float* Wr2   = (const float*)d_in[10];
    const float* Wp    = (const float*)d_in[11];
    const float* bp    = (const float*)d_in[12];
    const float* gamma = (const float*)d_in[13];
    const float* beta  = (const float*)d_in[14];

    const int IN = 100, INP = 128, H = 256, OUT = 256, P = 128;
    const int n = in_sizes[0] / IN;          // 100000
    const int E = in_sizes[1] / 2;           // 1600000
    const int* src = ei;
    const int* dst = ei + E;

    size_t off = 0;
    auto alloc = [&](size_t bytes) -> char* {
        char* p = (char*)d_ws + off;
        off += (bytes + 255) & ~(size_t)255;
        return p;
    };
    int*   counts   = (int*)alloc((size_t)n * 4);
    int*   cursor   = (int*)alloc((size_t)n * 4);
    int*   rp       = (int*)alloc((size_t)(n + 1) * 4);
    int*   partials = (int*)alloc(512 * 4);
    int*   col      = (int*)alloc(((size_t)E + 8 * (size_t)n) * 4);
    unsigned short* Wl0b = (unsigned short*)alloc((size_t)H * INP * 2);
    unsigned short* Wr0b = (unsigned short*)alloc((size_t)H * INP * 2);
    unsigned short* Wl1b = (unsigned short*)alloc((size_t)H * H * 2);
    unsigned short* Wr1b = (unsigned short*)alloc((size_t)H * H * 2);
    unsigned short* Wl2b = (unsigned short*)alloc((size_t)OUT * H * 2);
    unsigned short* Wr2b = (unsigned short*)alloc((size_t)OUT * H * 2);
    unsigned short* Wpb  = (unsigned short*)alloc((size_t)P * OUT * 2);
    float* bnsums   = (float*)alloc(256 * 4);
    float* bnparams = (float*)alloc(256 * 4);
    // gathered tables get n+1 rows (row n = zero row, pad target)
    unsigned short* xpad   = (unsigned short*)alloc((size_t)(n + 1) * INP * 2);
    unsigned short* aggpad = (unsigned short*)alloc((size_t)n * INP * 2);
    unsigned short* h1b    = (unsigned short*)alloc((size_t)(n + 1) * H * 2);
    unsigned short* agg1   = (unsigned short*)alloc((size_t)n * H * 2);
    unsigned short* h2b    = (unsigned short*)alloc((size_t)(n + 1) * H * 2);
    (void)alloc((size_t)256 * 512);                      // OOB guard for last-tile reads

    unsigned short* agg2 = h1b;                          // reuse (h1 dead in layer2)
    unsigned short* xb2  = xpad;                         // reuse xpad+aggpad region

    float* out_x = (float*)d_out;                  // [n][256] final x
    float* z     = out_x + (size_t)n * OUT;        // [n][128] projection/BN output

    const int nb = (n + 255) / 256;

    // --- CSR build (padded to multiples of 8, pad -> zero row n) ---
    zero_i32<<<nb, 256, 0, stream>>>(counts, n);
    zero_i32<<<nb, 256, 0, stream>>>(cursor, n);
    zero_f32<<<1, 256, 0, stream>>>(bnsums, 256);
    count_k<<<(E + 255) / 256, 256, 0, stream>>>(dst, counts, E);
    scan1<<<nb, 256, 0, stream>>>(counts, rp, partials, n);
    scan2<<<1, 512, 0, stream>>>(partials, nb);
    scan3<<<nb, 256, 0, stream>>>(rp, partials, n);
    fill_k<<<(E + 255) / 256, 256, 0, stream>>>(src, dst, rp, cursor, col, E);
    pad_fill<<<nb, 256, 0, stream>>>(rp, counts, col, n, n);

    // --- dtype conversions + zero rows ---
    conv_x_pad<<<(n * 32 + 255) / 256, 256, 0, stream>>>(x_in, xpad, n);
    zero_rows<<<1, 256, 0, stream>>>(xpad, h1b, h2b, n);
    conv_w<<<(H * INP + 255) / 256, 256, 0, stream>>>(Wl0, Wl0b, H, IN, INP);
    conv_w<<<(H * INP + 255) / 256, 256, 0, stream>>>(Wr0, Wr0b, H, IN, INP);
    conv_w<<<(H * H + 255) / 256, 256, 0, stream>>>(Wl1, Wl1b, H, H, H);
    conv_w<<<(H * H + 255) / 256, 256, 0, stream>>>(Wr1, Wr1b, H, H, H);
    conv_w<<<(OUT * H + 255) / 256, 256, 0, stream>>>(Wl2, Wl2b, OUT, H, H);
    conv_w<<<(OUT * H + 255) / 256, 256, 0, stream>>>(Wr2, Wr2b, OUT, H, H);
    conv_w<<<(P * OUT + 255) / 256, 256, 0, stream>>>(Wp, Wpb, P, OUT, OUT);

    const int gemm_grid = (n + 127) / 128;

    // --- layer 0: 128(pad) -> 256, relu ---
    agg_bf16_128<<<(n + 3) / 4, 256, 0, stream>>>(xpad, rp, counts, col, aggpad, n);
    sage_mfma<128, 256, true, true, false, true><<<gemm_grid, 512, 0, stream>>>(
        xpad, aggpad, Wr0b, Wl0b, bl0, nullptr, h1b, n);

    // --- layer 1: 256 -> 256, relu ---
    agg_bf16_256<<<(n + 3) / 4, 256, 0, stream>>>(h1b, rp, counts, col, agg1, n);
    sage_mfma<256, 256, true, true, false, true><<<gemm_grid, 512, 0, stream>>>(
        h1b, agg1, Wr1b, Wl1b, bl1, nullptr, h2b, n);

    // --- layer 2: 256 -> 256, no relu; f32 -> d_out, bf16 copy for projection ---
    agg_bf16_256<<<(n + 3) / 4, 256, 0, stream>>>(h2b, rp, counts, col, agg2, n);
    sage_mfma<256, 256, true, false, true, true><<<gemm_grid, 512, 0, stream>>>(
        h2b, agg2, Wr2b, Wl2b, bl2, out_x, xb2, n);

    // --- projection head: 256 -> 128 ---
    sage_mfma<256, 128, false, false, true, false><<<gemm_grid, 512, 0, stream>>>(
        xb2, nullptr, Wpb, nullptr, bp, z, nullptr, n);

    // --- BatchNorm over z ---
    bn_partial<<<256, 256, 0, stream>>>(z, bnsums, n);
    bn_finalize<<<1, 128, 0, stream>>>(bnsums, gamma, beta, bnparams, n);
    bn_apply<<<2048, 256, 0, stream>>>(z, bnparams, n * (P / 4));
}